// Round 6
// baseline (382.030 us; speedup 1.0000x reference)
//
#include <hip/hip_runtime.h>
#include <math.h>

#define N_BOX 8192
#define NW 128              // 8192 / 64 words per row
#define PFC 12              // prefetched candidate rows per group (ring slot)
#define THR_C 0.7f
#define IOU_THR_C 0.5f
#define EPS_C 1e-9f

// SCALER = max(3508/1280, 2480/1280) computed in double then rounded to f32,
// matching numpy/jax float32 weak-typed scalar promotion.
__device__ __constant__ float kScaler = (float)(3508.0 / 1280.0);

// async global->LDS DMA, 16 B/lane: lane l's 16 B land at ldsbase + l*16.
static __device__ __forceinline__ void gload_lds16(const void* gp, void* lp) {
    __builtin_amdgcn_global_load_lds(
        (const __attribute__((address_space(1))) unsigned int*)gp,
        (__attribute__((address_space(3))) unsigned int*)lp,
        16, 0, 0);
}

// broadcast 64-bit value from (wave-uniform) source lane via v_readlane
static __device__ __forceinline__ unsigned long long bcast64(unsigned long long v, int sl) {
    unsigned int lo = __builtin_amdgcn_readlane((unsigned int)(v & 0xffffffffull), sl);
    unsigned int hi = __builtin_amdgcn_readlane((unsigned int)(v >> 32), sl);
    return ((unsigned long long)hi << 32) | lo;
}

static __device__ __forceinline__ unsigned long long make_key(const float* conf, int i) {
    float c0 = conf[2 * i], c1 = conf[2 * i + 1];
    bool valid = (c0 > THR_C) || (c1 > THR_C);
    float ms = valid ? fmaxf(c0, c1) : -INFINITY;
    unsigned int u = __float_as_uint(ms);
    unsigned int m = (u & 0x80000000u) ? ~u : (u | 0x80000000u); // ascending map
    unsigned int d = ~m;                                          // descending key
    return ((unsigned long long)d << 32) | (unsigned int)i;
}

// ---------------------------------------------------------------------------
// Sort stage 1: 4 blocks x 2048 elements, all k<=2048 passes LDS-local.
// Directions use GLOBAL indices -> network identical to the verified
// single-block bitonic sort.
// ---------------------------------------------------------------------------
__global__ __launch_bounds__(1024) void sort_local1(const float* __restrict__ conf,
                                                    unsigned long long* __restrict__ keys) {
    __shared__ unsigned long long s[2048];
    int base = blockIdx.x * 2048;
    for (int l = threadIdx.x; l < 2048; l += 1024) s[l] = make_key(conf, base + l);
    __syncthreads();
    for (int k = 2; k <= 2048; k <<= 1) {
        for (int j = k >> 1; j > 0; j >>= 1) {
            int t = threadIdx.x;
            int i = ((t & ~(j - 1)) << 1) | (t & (j - 1));
            int p = i | j;
            bool up = (((base + i) & k) == 0);
            unsigned long long a = s[i], b = s[p];
            bool sw = up ? (a > b) : (a < b);
            if (sw) { s[i] = b; s[p] = a; }
            __syncthreads();
        }
    }
    for (int l = threadIdx.x; l < 2048; l += 1024) keys[base + l] = s[l];
}

// ---------------------------------------------------------------------------
// Sort stage 2: k=4096 merge, 2 blocks x 4096 elements (j=2048..1 all local
// to a 4096-half; directions from global index bit 4096).
// ---------------------------------------------------------------------------
__global__ __launch_bounds__(1024) void sort_mid(unsigned long long* __restrict__ keys) {
    __shared__ unsigned long long s[4096];
    int base = blockIdx.x * 4096;
    for (int l = threadIdx.x; l < 4096; l += 1024) s[l] = keys[base + l];
    __syncthreads();
    for (int j = 2048; j > 0; j >>= 1) {
        for (int t = threadIdx.x; t < 2048; t += 1024) {
            int i = ((t & ~(j - 1)) << 1) | (t & (j - 1));
            int p = i | j;
            bool up = (((base + i) & 4096) == 0);
            unsigned long long a = s[i], b = s[p];
            bool sw = up ? (a > b) : (a < b);
            if (sw) { s[i] = b; s[p] = a; }
        }
        __syncthreads();
    }
    for (int l = threadIdx.x; l < 4096; l += 1024) keys[base + l] = s[l];
}

// ---------------------------------------------------------------------------
// Sort stage 3 + gather: k=8192 merge. Each of 2 blocks loads ALL 8192 keys
// (redundant), does the j=4096 cross-half exchange for its own half in
// registers, then j=2048..1 locally (all ascending: (i & 8192)==0 for all i),
// then consumes the sorted half directly from LDS: writes sb/order/validw;
// block 0 zero-inits nzoffG for mask_kernel's atomicOr.
// ---------------------------------------------------------------------------
__global__ __launch_bounds__(1024) void sort_final(const unsigned long long* __restrict__ keys,
                                                   const float* __restrict__ bboxes,
                                                   const float* __restrict__ conf,
                                                   float4* __restrict__ sb,
                                                   unsigned int* __restrict__ order,
                                                   unsigned long long* __restrict__ validw,
                                                   unsigned long long* __restrict__ nzoffG) {
    __shared__ unsigned long long s[8192];   // 64 KiB
    int half = blockIdx.x;                   // 0 or 1
    int base = half << 12;
    for (int l = threadIdx.x; l < 8192; l += 1024) s[l] = keys[l];
    __syncthreads();
    // k=8192, j=4096: min -> low half, max -> high half (all ascending)
    unsigned long long v[4];
#pragma unroll
    for (int q = 0; q < 4; ++q) {
        int l = threadIdx.x + (q << 10);     // 0..4095 (low-half index)
        unsigned long long a = s[l], b = s[l + 4096];
        v[q] = half ? (a > b ? a : b) : (a > b ? b : a);
    }
    __syncthreads();
#pragma unroll
    for (int q = 0; q < 4; ++q) s[base + threadIdx.x + (q << 10)] = v[q];
    __syncthreads();
    // j=2048..1, local to own half; direction ascending everywhere (k=8192)
    for (int j = 2048; j > 0; j >>= 1) {
        for (int t = threadIdx.x; t < 2048; t += 1024) {
            int i = base + (((t & ~(j - 1)) << 1) | (t & (j - 1)));
            int p = i | j;
            unsigned long long a = s[i], b = s[p];
            if (a > b) { s[i] = b; s[p] = a; }
        }
        __syncthreads();
    }
    if (half == 0 && threadIdx.x < NW) nzoffG[threadIdx.x] = 0ull;
    for (int l = threadIdx.x; l < 4096; l += 1024) {
        int gi = base + l;
        unsigned int o = (unsigned int)(s[gi] & 0xffffffffull);
        order[gi] = o;
        sb[gi] = ((const float4*)bboxes)[o];
        float c0 = conf[2 * o], c1 = conf[2 * o + 1];
        unsigned long long vb = __ballot((c0 > THR_C) || (c1 > THR_C));
        if ((gi & 63) == 0) validw[gi >> 6] = vb;
    }
}

// ---------------------------------------------------------------------------
// Kernel 3: suppression bit-matrix + sparsity metadata.
//   mask[i][w] bit b = (iou(i, 64w+b) > thr && 64w+b > i)
//   diagG[i]  = mask[i][i>>6]; dnzG[w] bit r = diag word nonzero;
//   nzoffG[w] bit r = row 64w+r has a nonzero off-diagonal word.
// Invalid rows and lower-triangle words skip all work (never read downstream).
// ---------------------------------------------------------------------------
__global__ void mask_kernel(const float4* __restrict__ sb,
                            const unsigned long long* __restrict__ validw,
                            unsigned long long* __restrict__ mask,
                            unsigned long long* __restrict__ diagG,
                            unsigned long long* __restrict__ dnzG,
                            unsigned long long* __restrict__ nzoffG) {
    __shared__ float4 cb[64];
    __shared__ float carea[64];
    int w = blockIdx.y;
    if (threadIdx.x < 64) {
        float4 c = sb[(w << 6) + threadIdx.x];
        cb[threadIdx.x] = c;
        carea[threadIdx.x] = (c.z - c.x) * (c.w - c.y);
    }
    __syncthreads();
    int i = blockIdx.x * 256 + threadIdx.x;
    bool iv = (validw[i >> 6] >> (i & 63)) & 1ull;
    int jbase = w << 6;
    unsigned long long bits = 0ull;
    if (iv && (jbase + 63 > i)) {
        float4 r = sb[i];
        float ra = (r.z - r.x) * (r.w - r.y);
#pragma unroll 8
        for (int b = 0; b < 64; ++b) {
            float4 c = cb[b];
            float iw = fminf(r.z, c.z) - fmaxf(r.x, c.x);
            float ih = fminf(r.w, c.w) - fmaxf(r.y, c.y);
            iw = fmaxf(iw, 0.0f);
            ih = fmaxf(ih, 0.0f);
            float inter = iw * ih;
            float iou = inter / (ra + carea[b] - inter + EPS_C);
            if ((iou > IOU_THR_C) && ((jbase + b) > i)) bits |= (1ull << b);
        }
    }
    unsigned long long bb = __ballot(bits != 0ull);
    if ((i >> 6) == w) {
        diagG[i] = bits;
        if ((i & 63) == 0) dnzG[w] = bb;
    } else {
        if (bb && ((i & 63) == 0)) atomicOr(&nzoffG[i >> 6], bb);
    }
    if (iv) mask[(size_t)i * NW + w] = bits;
}

// ---------------------------------------------------------------------------
// Kernel 4: single-wave greedy scan, no barriers, with a 4-deep register
// prefetch ring for apply rows. Candidate superset for group g
// (nzoff[g] & ~rem at issue time) is valid because rem only grows and kept
// rows are never removed; actual rows applied are filtered by kw at apply.
// Diag words: up to 8 independent LDS loads hoisted ahead of the serial
// OR chain (one latency instead of one per row).
// ---------------------------------------------------------------------------
#define ISSUE(pfA, slot, gq) do {                                              \
    if ((gq) < NW) {                                                           \
        unsigned long long rw = bcast64(((gq) < 64) ? r0 : r1, (gq) & 63);     \
        unsigned long long cq = nzoffL[gq] & ~rw;                              \
        cwp[slot] = cq;                                                        \
        const unsigned long long* mb = mask + ((size_t)(gq) << 6) * NW;        \
        _Pragma("unroll")                                                      \
        for (int j = 0; j < PFC; ++j) {                                        \
            int rr = cq ? __builtin_ctzll(cq) : 0;                             \
            cq &= cq - 1;                                                      \
            pfA[j][0] = mb[(size_t)rr * NW + lane];                            \
            pfA[j][1] = mb[(size_t)rr * NW + lane + 64];                       \
        }                                                                      \
    } else { cwp[slot] = 0ull; }                                               \
} while (0)

#define APPLY(pfA, slot, g) do {                                               \
    unsigned long long cur = bcast64(((g) < 64) ? r0 : r1, (g) & 63);          \
    unsigned long long dtmp = dnzL[g];                                         \
    int dr_[8]; unsigned long long dv_[8];                                     \
    _Pragma("unroll")                                                          \
    for (int j = 0; j < 8; ++j) {                                              \
        int rr = dtmp ? __builtin_ctzll(dtmp) : -1;                            \
        dtmp &= dtmp - 1;                                                      \
        dr_[j] = rr;                                                           \
        dv_[j] = diagL[((g) << 6) + (rr & 63)];                                \
    }                                                                          \
    _Pragma("unroll")                                                          \
    for (int j = 0; j < 8; ++j)                                                \
        if (dr_[j] >= 0 && !((cur >> dr_[j]) & 1ull)) cur |= dv_[j];           \
    while (dtmp) {                                                             \
        int rr = __builtin_ctzll(dtmp); dtmp &= dtmp - 1;                      \
        if (!((cur >> rr) & 1ull)) cur |= diagL[((g) << 6) + rr];              \
    }                                                                          \
    if (lane == 0) keepL[g] = cur;                                             \
    unsigned long long kwv = ~cur;                                             \
    unsigned long long tmp = cwp[slot];                                        \
    _Pragma("unroll")                                                          \
    for (int j = 0; j < PFC; ++j) {                                            \
        int rr = tmp ? __builtin_ctzll(tmp) : -1;                              \
        tmp &= tmp - 1;                                                        \
        if (rr >= 0 && ((kwv >> rr) & 1ull)) { r0 |= pfA[j][0]; r1 |= pfA[j][1]; } \
    }                                                                          \
    while (tmp) {                                                              \
        int rr = __builtin_ctzll(tmp); tmp &= tmp - 1;                         \
        if ((kwv >> rr) & 1ull) {                                              \
            const unsigned long long* mrow = mask + (size_t)(((g) << 6) + rr) * NW; \
            r0 |= mrow[lane]; r1 |= mrow[lane + 64];                           \
        }                                                                      \
    }                                                                          \
} while (0)

__global__ __launch_bounds__(64) void scan_kernel(const unsigned long long* __restrict__ mask,
                                                  const unsigned long long* __restrict__ validw,
                                                  const unsigned long long* __restrict__ diagG,
                                                  const unsigned long long* __restrict__ dnzG,
                                                  const unsigned long long* __restrict__ nzoffG,
                                                  unsigned long long* __restrict__ keepw) {
    __shared__ unsigned long long diagL[N_BOX];   // 64 KiB
    __shared__ unsigned long long dnzL[NW];
    __shared__ unsigned long long nzoffL[NW];
    __shared__ unsigned long long keepL[NW];
    int lane = threadIdx.x;
    for (int c = 0; c < 64; ++c)
        gload_lds16((const char*)diagG + (c << 10) + lane * 16,
                    (char*)diagL + (c << 10));
    dnzL[lane] = dnzG[lane];
    dnzL[lane + 64] = dnzG[lane + 64];
    nzoffL[lane] = nzoffG[lane];
    nzoffL[lane + 64] = nzoffG[lane + 64];
    unsigned long long r0 = ~validw[lane];        // removal words 0..63
    unsigned long long r1 = ~validw[lane + 64];   // removal words 64..127
    __builtin_amdgcn_s_waitcnt(0);                // drain DMA + loads

    unsigned long long pf0[PFC][2], pf1[PFC][2], pf2[PFC][2], pf3[PFC][2];
    unsigned long long cwp[4];
    ISSUE(pf0, 0, 0); ISSUE(pf1, 1, 1); ISSUE(pf2, 2, 2); ISSUE(pf3, 3, 3);
    for (int g = 0; g < NW; g += 4) {
        APPLY(pf0, 0, g);     ISSUE(pf0, 0, g + 4);
        APPLY(pf1, 1, g + 1); ISSUE(pf1, 1, g + 5);
        APPLY(pf2, 2, g + 2); ISSUE(pf2, 2, g + 6);
        APPLY(pf3, 3, g + 3); ISSUE(pf3, 3, g + 7);
    }
    keepw[lane] = keepL[lane];
    keepw[lane + 64] = keepL[lane + 64];
}

// ---------------------------------------------------------------------------
// Kernel 5: write (N,6) output: [boxes*SCALER*kf, conf*kf]
// ---------------------------------------------------------------------------
__global__ void out_kernel(const float4* __restrict__ sb,
                           const unsigned long long* __restrict__ keepw,
                           const unsigned int* __restrict__ order,
                           const float* __restrict__ conf,
                           float* __restrict__ out) {
    int i = blockIdx.x * 256 + threadIdx.x;
    float kf = ((keepw[i >> 6] >> (i & 63)) & 1ull) ? 0.0f : 1.0f;
    float4 b = sb[i];
    unsigned int o = order[i];
    float s = kScaler * kf;
    out[i * 6 + 0] = b.x * s;
    out[i * 6 + 1] = b.y * s;
    out[i * 6 + 2] = b.z * s;
    out[i * 6 + 3] = b.w * s;
    out[i * 6 + 4] = conf[2 * o] * kf;
    out[i * 6 + 5] = conf[2 * o + 1] * kf;
}

extern "C" void kernel_launch(void* const* d_in, const int* in_sizes, int n_in,
                              void* d_out, int out_size, void* d_ws, size_t ws_size,
                              hipStream_t stream) {
    const float* cls_conf = (const float*)d_in[0];   // (8192, 2)
    const float* bboxes   = (const float*)d_in[1];   // (8192, 4)
    float* out = (float*)d_out;                      // (8192, 6)

    char* ws = (char*)d_ws;
    unsigned long long* keys   = (unsigned long long*)(ws + 0);        //  64 KiB
    float4*             sb     = (float4*)(ws + 65536);                // 128 KiB
    unsigned int*       order  = (unsigned int*)(ws + 196608);         //  32 KiB
    unsigned long long* validw = (unsigned long long*)(ws + 229376);   //   1 KiB
    unsigned long long* mask   = (unsigned long long*)(ws + 237568);   //   8 MiB
    unsigned long long* keepw  = (unsigned long long*)(ws + 8626176);  //   1 KiB
    unsigned long long* diagG  = (unsigned long long*)(ws + 8627200);  //  64 KiB
    unsigned long long* dnzG   = (unsigned long long*)(ws + 8692736);  //   1 KiB
    unsigned long long* nzoffG = (unsigned long long*)(ws + 8693760);  //   1 KiB

    sort_local1<<<4, 1024, 0, stream>>>(cls_conf, keys);
    sort_mid<<<2, 1024, 0, stream>>>(keys);
    sort_final<<<2, 1024, 0, stream>>>(keys, bboxes, cls_conf, sb, order, validw, nzoffG);
    mask_kernel<<<dim3(32, 128), 256, 0, stream>>>(sb, validw, mask, diagG, dnzG, nzoffG);
    scan_kernel<<<1, 64, 0, stream>>>(mask, validw, diagG, dnzG, nzoffG, keepw);
    out_kernel<<<N_BOX / 256, 256, 0, stream>>>(sb, keepw, order, cls_conf, out);
}

// Round 7
// 333.081 us; speedup vs baseline: 1.1470x; 1.1470x over previous
//
#include <hip/hip_runtime.h>
#include <math.h>

#define N_BOX 8192
#define NW 128              // 8192 / 64 words per row
#define GCAP 128            // max stored edges per 64-row group
#define THR_C 0.7f
#define IOU_THR_C 0.5f
#define EPS_C 1e-9f

// SCALER = max(3508/1280, 2480/1280) computed in double then rounded to f32,
// matching numpy/jax float32 weak-typed scalar promotion.
__device__ __constant__ float kScaler = (float)(3508.0 / 1280.0);

// async global->LDS DMA, 16 B/lane: lane l's 16 B land at ldsbase + l*16.
static __device__ __forceinline__ void gload_lds16(const void* gp, void* lp) {
    __builtin_amdgcn_global_load_lds(
        (const __attribute__((address_space(1))) unsigned int*)gp,
        (__attribute__((address_space(3))) unsigned int*)lp,
        16, 0, 0);
}

// broadcast 64-bit value from (wave-uniform) source lane via v_readlane
static __device__ __forceinline__ unsigned long long bcast64(unsigned long long v, int sl) {
    unsigned int lo = __builtin_amdgcn_readlane((unsigned int)(v & 0xffffffffull), sl);
    unsigned int hi = __builtin_amdgcn_readlane((unsigned int)(v >> 32), sl);
    return ((unsigned long long)hi << 32) | lo;
}

static __device__ __forceinline__ unsigned long long make_key(const float* conf, int i) {
    float c0 = conf[2 * i], c1 = conf[2 * i + 1];
    bool valid = (c0 > THR_C) || (c1 > THR_C);
    float ms = valid ? fmaxf(c0, c1) : -INFINITY;
    unsigned int u = __float_as_uint(ms);
    unsigned int m = (u & 0x80000000u) ? ~u : (u | 0x80000000u); // ascending map
    unsigned int d = ~m;                                          // descending key
    return ((unsigned long long)d << 32) | (unsigned int)i;
}

// ---------------------------------------------------------------------------
// Sort stage 1: 4 blocks x 2048 elements, all k<=2048 passes LDS-local.
// Directions use GLOBAL indices -> network identical to the verified
// single-block bitonic sort.
// ---------------------------------------------------------------------------
__global__ __launch_bounds__(1024) void sort_local1(const float* __restrict__ conf,
                                                    unsigned long long* __restrict__ keys) {
    __shared__ unsigned long long s[2048];
    int base = blockIdx.x * 2048;
    for (int l = threadIdx.x; l < 2048; l += 1024) s[l] = make_key(conf, base + l);
    __syncthreads();
    for (int k = 2; k <= 2048; k <<= 1) {
        for (int j = k >> 1; j > 0; j >>= 1) {
            int t = threadIdx.x;
            int i = ((t & ~(j - 1)) << 1) | (t & (j - 1));
            int p = i | j;
            bool up = (((base + i) & k) == 0);
            unsigned long long a = s[i], b = s[p];
            bool sw = up ? (a > b) : (a < b);
            if (sw) { s[i] = b; s[p] = a; }
            __syncthreads();
        }
    }
    for (int l = threadIdx.x; l < 2048; l += 1024) keys[base + l] = s[l];
}

// ---------------------------------------------------------------------------
// Sort stage 2: k=4096 merge, 2 blocks x 4096 elements (j=2048..1 all local
// to a 4096-half; directions from global index bit 4096).
// ---------------------------------------------------------------------------
__global__ __launch_bounds__(1024) void sort_mid(unsigned long long* __restrict__ keys) {
    __shared__ unsigned long long s[4096];
    int base = blockIdx.x * 4096;
    for (int l = threadIdx.x; l < 4096; l += 1024) s[l] = keys[base + l];
    __syncthreads();
    for (int j = 2048; j > 0; j >>= 1) {
        for (int t = threadIdx.x; t < 2048; t += 1024) {
            int i = ((t & ~(j - 1)) << 1) | (t & (j - 1));
            int p = i | j;
            bool up = (((base + i) & 4096) == 0);
            unsigned long long a = s[i], b = s[p];
            bool sw = up ? (a > b) : (a < b);
            if (sw) { s[i] = b; s[p] = a; }
        }
        __syncthreads();
    }
    for (int l = threadIdx.x; l < 4096; l += 1024) keys[base + l] = s[l];
}

// ---------------------------------------------------------------------------
// Sort stage 3 + gather: k=8192 merge. Each of 2 blocks loads ALL 8192 keys
// (redundant), does the j=4096 cross-half exchange for its own half in
// registers, then j=2048..1 locally (all ascending), then consumes the sorted
// half directly from LDS: writes sb/order/validw; zero-inits nzoffG and ecntG
// for mask_kernel's atomics.
// ---------------------------------------------------------------------------
__global__ __launch_bounds__(1024) void sort_final(const unsigned long long* __restrict__ keys,
                                                   const float* __restrict__ bboxes,
                                                   const float* __restrict__ conf,
                                                   float4* __restrict__ sb,
                                                   unsigned int* __restrict__ order,
                                                   unsigned long long* __restrict__ validw,
                                                   unsigned long long* __restrict__ nzoffG,
                                                   int* __restrict__ ecntG) {
    __shared__ unsigned long long s[8192];   // 64 KiB
    int half = blockIdx.x;                   // 0 or 1
    int base = half << 12;
    for (int l = threadIdx.x; l < 8192; l += 1024) s[l] = keys[l];
    __syncthreads();
    unsigned long long v[4];
#pragma unroll
    for (int q = 0; q < 4; ++q) {
        int l = threadIdx.x + (q << 10);
        unsigned long long a = s[l], b = s[l + 4096];
        v[q] = half ? (a > b ? a : b) : (a > b ? b : a);
    }
    __syncthreads();
#pragma unroll
    for (int q = 0; q < 4; ++q) s[base + threadIdx.x + (q << 10)] = v[q];
    __syncthreads();
    for (int j = 2048; j > 0; j >>= 1) {
        for (int t = threadIdx.x; t < 2048; t += 1024) {
            int i = base + (((t & ~(j - 1)) << 1) | (t & (j - 1)));
            int p = i | j;
            unsigned long long a = s[i], b = s[p];
            if (a > b) { s[i] = b; s[p] = a; }
        }
        __syncthreads();
    }
    if (half == 0 && threadIdx.x < NW) { nzoffG[threadIdx.x] = 0ull; ecntG[threadIdx.x] = 0; }
    for (int l = threadIdx.x; l < 4096; l += 1024) {
        int gi = base + l;
        unsigned int o = (unsigned int)(s[gi] & 0xffffffffull);
        order[gi] = o;
        sb[gi] = ((const float4*)bboxes)[o];
        float c0 = conf[2 * o], c1 = conf[2 * o + 1];
        unsigned long long vb = __ballot((c0 > THR_C) || (c1 > THR_C));
        if ((gi & 63) == 0) validw[gi >> 6] = vb;
    }
}

// ---------------------------------------------------------------------------
// Kernel 3: suppression bit-matrix + sparsity metadata + COMPACT EDGE LIST.
//   mask[i][w] bit b = (iou(i, 64w+b) > thr && 64w+b > i)
//   diagG[i]  = mask[i][i>>6]; dnzG[w] bit r = diag word nonzero;
//   nzoffG[w] bit r = row 64w+r has a nonzero off-diagonal word;
//   egrpG[g][slot] = (srcRow&63)<<13 | target   (off-diag edges of group g,
//   capped at GCAP; ecntG[g] counts all — scan falls back to mask rows if
//   ecnt > GCAP). Off-diag edges always target later groups (upper triangle),
//   so in-group decisions depend only on diag words.
// ---------------------------------------------------------------------------
__global__ void mask_kernel(const float4* __restrict__ sb,
                            const unsigned long long* __restrict__ validw,
                            unsigned long long* __restrict__ mask,
                            unsigned long long* __restrict__ diagG,
                            unsigned long long* __restrict__ dnzG,
                            unsigned long long* __restrict__ nzoffG,
                            int* __restrict__ ecntG,
                            unsigned int* __restrict__ egrpG) {
    __shared__ float4 cb[64];
    __shared__ float carea[64];
    int w = blockIdx.y;
    if (threadIdx.x < 64) {
        float4 c = sb[(w << 6) + threadIdx.x];
        cb[threadIdx.x] = c;
        carea[threadIdx.x] = (c.z - c.x) * (c.w - c.y);
    }
    __syncthreads();
    int i = blockIdx.x * 256 + threadIdx.x;
    bool iv = (validw[i >> 6] >> (i & 63)) & 1ull;
    int jbase = w << 6;
    unsigned long long bits = 0ull;
    if (iv && (jbase + 63 > i)) {
        float4 r = sb[i];
        float ra = (r.z - r.x) * (r.w - r.y);
#pragma unroll 8
        for (int b = 0; b < 64; ++b) {
            float4 c = cb[b];
            float iw = fminf(r.z, c.z) - fmaxf(r.x, c.x);
            float ih = fminf(r.w, c.w) - fmaxf(r.y, c.y);
            iw = fmaxf(iw, 0.0f);
            ih = fmaxf(ih, 0.0f);
            float inter = iw * ih;
            float iou = inter / (ra + carea[b] - inter + EPS_C);
            if ((iou > IOU_THR_C) && ((jbase + b) > i)) bits |= (1ull << b);
        }
    }
    unsigned long long bb = __ballot(bits != 0ull);
    int g = i >> 6;
    if (g == w) {
        diagG[i] = bits;
        if ((i & 63) == 0) dnzG[w] = bb;
    } else {
        if (bb && ((i & 63) == 0)) atomicOr(&nzoffG[g], bb);
        if (bits) {                       // append off-diag edges
            unsigned int rs = (unsigned int)(i & 63) << 13;
            unsigned long long tb = bits;
            while (tb) {
                int b = __builtin_ctzll(tb); tb &= tb - 1;
                int slot = atomicAdd(&ecntG[g], 1);
                if (slot < GCAP) egrpG[g * GCAP + slot] = rs | (unsigned int)(jbase + b);
            }
        }
    }
    if (iv) mask[(size_t)i * NW + w] = bits;
}

// ---------------------------------------------------------------------------
// Kernel 4: single-wave greedy scan over the COMPACT EDGE LIST. No barriers,
// no memory on the critical path:
//   - diag words LDS-resident (DMA'd once); in-group serial scan as before;
//   - off-diag suppression applied edge-by-edge via readlane broadcast from a
//     4-deep register ring whose load addresses are STATIC (egrp layout), so
//     prefetch never depends on rem — perfectly pipelined;
//   - overflow groups (ecnt > GCAP, expected none) fall back to mask rows.
// ---------------------------------------------------------------------------
#define APPLYE(ed) do {                                                        \
    int rr_ = (int)((ed) >> 13);                                               \
    if ((kwv >> rr_) & 1ull) {                                                 \
        int tt_ = (int)((ed) & 8191u);                                         \
        unsigned long long bt_ = 1ull << (tt_ & 63);                           \
        int tw_ = tt_ >> 6;                                                    \
        if (tw_ == lane) r0 |= bt_;                                            \
        if (tw_ == lane + 64) r1 |= bt_;                                       \
    }                                                                          \
} while (0)

#define STEP(s, g) do {                                                        \
    int cnt = cntS[s];                                                         \
    unsigned long long cur = bcast64(((g) < 64) ? r0 : r1, (g) & 63);          \
    unsigned long long dn = dnzL[g];                                           \
    int dr_[8]; unsigned long long dv_[8];                                     \
    _Pragma("unroll")                                                          \
    for (int j = 0; j < 8; ++j) {                                              \
        int rr = dn ? __builtin_ctzll(dn) : -1;                                \
        dn &= dn - 1;                                                          \
        dr_[j] = rr;                                                           \
        dv_[j] = diagL[((g) << 6) + (rr & 63)];                                \
    }                                                                          \
    _Pragma("unroll")                                                          \
    for (int j = 0; j < 8; ++j)                                                \
        if (dr_[j] >= 0 && !((cur >> dr_[j]) & 1ull)) cur |= dv_[j];           \
    while (dn) {                                                               \
        int rr = __builtin_ctzll(dn); dn &= dn - 1;                            \
        if (!((cur >> rr) & 1ull)) cur |= diagL[((g) << 6) + rr];              \
    }                                                                          \
    if (lane == 0) keepL[g] = cur;                                             \
    unsigned long long kwv = ~cur;                                             \
    if (cnt <= GCAP) {                                                         \
        int c0_ = cnt < 64 ? cnt : 64;                                         \
        for (int e = 0; e < c0_; ++e) {                                        \
            unsigned int ed = __builtin_amdgcn_readlane(erA[s], e);            \
            APPLYE(ed);                                                        \
        }                                                                      \
        for (int e = 64; e < cnt; ++e) {                                       \
            unsigned int ed = __builtin_amdgcn_readlane(erB[s], e - 64);       \
            APPLYE(ed);                                                        \
        }                                                                      \
    } else {                                                                   \
        unsigned long long cw = kwv & nzoffL[g];                               \
        while (cw) {                                                           \
            int a0 = __builtin_ctzll(cw); cw &= cw - 1;                        \
            int a1 = a0, a2 = a0, a3 = a0;                                     \
            if (cw) { a1 = __builtin_ctzll(cw); cw &= cw - 1; }                \
            if (cw) { a2 = __builtin_ctzll(cw); cw &= cw - 1; }                \
            if (cw) { a3 = __builtin_ctzll(cw); cw &= cw - 1; }                \
            const unsigned long long* m0 = mask + (size_t)(((g) << 6) + a0) * NW; \
            const unsigned long long* m1 = mask + (size_t)(((g) << 6) + a1) * NW; \
            const unsigned long long* m2 = mask + (size_t)(((g) << 6) + a2) * NW; \
            const unsigned long long* m3 = mask + (size_t)(((g) << 6) + a3) * NW; \
            r0 |= m0[lane] | m1[lane] | m2[lane] | m3[lane];                   \
            r1 |= m0[lane + 64] | m1[lane + 64] | m2[lane + 64] | m3[lane + 64]; \
        }                                                                      \
    }                                                                          \
    if ((g) + 4 < NW) {                                                        \
        erA[s] = egrp[((g) + 4) * GCAP + lane];                                \
        erB[s] = egrp[((g) + 4) * GCAP + 64 + lane];                           \
        cntS[s] = cntL[(g) + 4];                                               \
    }                                                                          \
} while (0)

__global__ __launch_bounds__(64) void scan_kernel(const unsigned long long* __restrict__ mask,
                                                  const unsigned long long* __restrict__ validw,
                                                  const unsigned long long* __restrict__ diagG,
                                                  const unsigned long long* __restrict__ dnzG,
                                                  const unsigned long long* __restrict__ nzoffG,
                                                  const int* __restrict__ ecntG,
                                                  const unsigned int* __restrict__ egrp,
                                                  unsigned long long* __restrict__ keepw) {
    __shared__ unsigned long long diagL[N_BOX];   // 64 KiB
    __shared__ unsigned long long dnzL[NW];
    __shared__ unsigned long long nzoffL[NW];
    __shared__ unsigned long long keepL[NW];
    __shared__ int cntL[NW];
    int lane = threadIdx.x;
    for (int c = 0; c < 64; ++c)
        gload_lds16((const char*)diagG + (c << 10) + lane * 16,
                    (char*)diagL + (c << 10));
    dnzL[lane] = dnzG[lane];
    dnzL[lane + 64] = dnzG[lane + 64];
    nzoffL[lane] = nzoffG[lane];
    nzoffL[lane + 64] = nzoffG[lane + 64];
    cntL[lane] = ecntG[lane];
    cntL[lane + 64] = ecntG[lane + 64];
    unsigned long long r0 = ~validw[lane];        // removal words 0..63
    unsigned long long r1 = ~validw[lane + 64];   // removal words 64..127
    __builtin_amdgcn_s_waitcnt(0);                // drain DMA + loads

    unsigned int erA[4], erB[4];
    int cntS[4];
#pragma unroll
    for (int s = 0; s < 4; ++s) {
        erA[s] = egrp[s * GCAP + lane];
        erB[s] = egrp[s * GCAP + 64 + lane];
        cntS[s] = cntL[s];
    }
    for (int g = 0; g < NW; g += 4) {
        STEP(0, g);
        STEP(1, g + 1);
        STEP(2, g + 2);
        STEP(3, g + 3);
    }
    keepw[lane] = keepL[lane];
    keepw[lane + 64] = keepL[lane + 64];
}

// ---------------------------------------------------------------------------
// Kernel 5: write (N,6) output: [boxes*SCALER*kf, conf*kf]
// ---------------------------------------------------------------------------
__global__ void out_kernel(const float4* __restrict__ sb,
                           const unsigned long long* __restrict__ keepw,
                           const unsigned int* __restrict__ order,
                           const float* __restrict__ conf,
                           float* __restrict__ out) {
    int i = blockIdx.x * 256 + threadIdx.x;
    float kf = ((keepw[i >> 6] >> (i & 63)) & 1ull) ? 0.0f : 1.0f;
    float4 b = sb[i];
    unsigned int o = order[i];
    float s = kScaler * kf;
    out[i * 6 + 0] = b.x * s;
    out[i * 6 + 1] = b.y * s;
    out[i * 6 + 2] = b.z * s;
    out[i * 6 + 3] = b.w * s;
    out[i * 6 + 4] = conf[2 * o] * kf;
    out[i * 6 + 5] = conf[2 * o + 1] * kf;
}

extern "C" void kernel_launch(void* const* d_in, const int* in_sizes, int n_in,
                              void* d_out, int out_size, void* d_ws, size_t ws_size,
                              hipStream_t stream) {
    const float* cls_conf = (const float*)d_in[0];   // (8192, 2)
    const float* bboxes   = (const float*)d_in[1];   // (8192, 4)
    float* out = (float*)d_out;                      // (8192, 6)

    char* ws = (char*)d_ws;
    unsigned long long* keys   = (unsigned long long*)(ws + 0);        //  64 KiB (dead after sort_final)
    unsigned int*       egrpG  = (unsigned int*)(ws + 0);              //  64 KiB (aliases keys)
    float4*             sb     = (float4*)(ws + 65536);                // 128 KiB
    unsigned int*       order  = (unsigned int*)(ws + 196608);         //  32 KiB
    unsigned long long* validw = (unsigned long long*)(ws + 229376);   //   1 KiB
    unsigned long long* mask   = (unsigned long long*)(ws + 237568);   //   8 MiB
    unsigned long long* keepw  = (unsigned long long*)(ws + 8626176);  //   1 KiB
    unsigned long long* diagG  = (unsigned long long*)(ws + 8627200);  //  64 KiB
    unsigned long long* dnzG   = (unsigned long long*)(ws + 8692736);  //   1 KiB
    unsigned long long* nzoffG = (unsigned long long*)(ws + 8693760);  //   1 KiB
    int*                ecntG  = (int*)(ws + 8694784);                 // 512 B

    sort_local1<<<4, 1024, 0, stream>>>(cls_conf, keys);
    sort_mid<<<2, 1024, 0, stream>>>(keys);
    sort_final<<<2, 1024, 0, stream>>>(keys, bboxes, cls_conf, sb, order, validw,
                                       nzoffG, ecntG);
    mask_kernel<<<dim3(32, 128), 256, 0, stream>>>(sb, validw, mask, diagG, dnzG,
                                                   nzoffG, ecntG, egrpG);
    scan_kernel<<<1, 64, 0, stream>>>(mask, validw, diagG, dnzG, nzoffG, ecntG,
                                      egrpG, keepw);
    out_kernel<<<N_BOX / 256, 256, 0, stream>>>(sb, keepw, order, cls_conf, out);
}

// Round 8
// 155.481 us; speedup vs baseline: 2.4571x; 2.1423x over previous
//
#include <hip/hip_runtime.h>
#include <math.h>

#define N_BOX 8192
#define NW 128              // 8192 / 64 words per row
#define LCAP 24576          // edges staged in LDS (96 KiB)
#define ECAP_MAX 262144     // max edges in global buffer (1 MiB)
#define THR_C 0.7f
#define IOU_THR_C 0.5f
#define EPS_C 1e-9f

// SCALER = max(3508/1280, 2480/1280) computed in double then rounded to f32,
// matching numpy/jax float32 weak-typed scalar promotion.
__device__ __constant__ float kScaler = (float)(3508.0 / 1280.0);

// broadcast 64-bit value from (wave-uniform) source lane via v_readlane
static __device__ __forceinline__ unsigned long long bcast64(unsigned long long v, int sl) {
    unsigned int lo = __builtin_amdgcn_readlane((unsigned int)(v & 0xffffffffull), sl);
    unsigned int hi = __builtin_amdgcn_readlane((unsigned int)(v >> 32), sl);
    return ((unsigned long long)hi << 32) | lo;
}

static __device__ __forceinline__ unsigned long long make_key(const float* conf, int i) {
    float c0 = conf[2 * i], c1 = conf[2 * i + 1];
    bool valid = (c0 > THR_C) || (c1 > THR_C);
    float ms = valid ? fmaxf(c0, c1) : -INFINITY;
    unsigned int u = __float_as_uint(ms);
    unsigned int m = (u & 0x80000000u) ? ~u : (u | 0x80000000u); // ascending map
    unsigned int d = ~m;                                          // descending key
    return ((unsigned long long)d << 32) | (unsigned int)i;
}

// ---------------------------------------------------------------------------
// Sort stage 1: 4 blocks x 2048 elements, all k<=2048 passes LDS-local.
// Directions use GLOBAL indices -> network identical to the verified
// single-block bitonic sort.
// ---------------------------------------------------------------------------
__global__ __launch_bounds__(1024) void sort_local1(const float* __restrict__ conf,
                                                    unsigned long long* __restrict__ keys) {
    __shared__ unsigned long long s[2048];
    int base = blockIdx.x * 2048;
    for (int l = threadIdx.x; l < 2048; l += 1024) s[l] = make_key(conf, base + l);
    __syncthreads();
    for (int k = 2; k <= 2048; k <<= 1) {
        for (int j = k >> 1; j > 0; j >>= 1) {
            int t = threadIdx.x;
            int i = ((t & ~(j - 1)) << 1) | (t & (j - 1));
            int p = i | j;
            bool up = (((base + i) & k) == 0);
            unsigned long long a = s[i], b = s[p];
            bool sw = up ? (a > b) : (a < b);
            if (sw) { s[i] = b; s[p] = a; }
            __syncthreads();
        }
    }
    for (int l = threadIdx.x; l < 2048; l += 1024) keys[base + l] = s[l];
}

// ---------------------------------------------------------------------------
// Sort stage 2: k=4096 merge, 2 blocks x 4096 elements (j=2048..1 all local
// to a 4096-half; directions from global index bit 4096).
// ---------------------------------------------------------------------------
__global__ __launch_bounds__(1024) void sort_mid(unsigned long long* __restrict__ keys) {
    __shared__ unsigned long long s[4096];
    int base = blockIdx.x * 4096;
    for (int l = threadIdx.x; l < 4096; l += 1024) s[l] = keys[base + l];
    __syncthreads();
    for (int j = 2048; j > 0; j >>= 1) {
        for (int t = threadIdx.x; t < 2048; t += 1024) {
            int i = ((t & ~(j - 1)) << 1) | (t & (j - 1));
            int p = i | j;
            bool up = (((base + i) & 4096) == 0);
            unsigned long long a = s[i], b = s[p];
            bool sw = up ? (a > b) : (a < b);
            if (sw) { s[i] = b; s[p] = a; }
        }
        __syncthreads();
    }
    for (int l = threadIdx.x; l < 4096; l += 1024) keys[base + l] = s[l];
}

// ---------------------------------------------------------------------------
// Sort stage 3 + gather: k=8192 merge. Each of 2 blocks loads ALL 8192 keys
// (redundant), does the j=4096 cross-half exchange for its own half, then
// j=2048..1 locally (all ascending), then consumes the sorted half directly
// from LDS: writes sb/order/validw; zero-inits the edge counter.
// ---------------------------------------------------------------------------
__global__ __launch_bounds__(1024) void sort_final(const unsigned long long* __restrict__ keys,
                                                   const float* __restrict__ bboxes,
                                                   const float* __restrict__ conf,
                                                   float4* __restrict__ sb,
                                                   unsigned int* __restrict__ order,
                                                   unsigned long long* __restrict__ validw,
                                                   int* __restrict__ ecntE) {
    __shared__ unsigned long long s[8192];   // 64 KiB
    int half = blockIdx.x;                   // 0 or 1
    int base = half << 12;
    for (int l = threadIdx.x; l < 8192; l += 1024) s[l] = keys[l];
    __syncthreads();
    unsigned long long v[4];
#pragma unroll
    for (int q = 0; q < 4; ++q) {
        int l = threadIdx.x + (q << 10);
        unsigned long long a = s[l], b = s[l + 4096];
        v[q] = half ? (a > b ? a : b) : (a > b ? b : a);
    }
    __syncthreads();
#pragma unroll
    for (int q = 0; q < 4; ++q) s[base + threadIdx.x + (q << 10)] = v[q];
    __syncthreads();
    for (int j = 2048; j > 0; j >>= 1) {
        for (int t = threadIdx.x; t < 2048; t += 1024) {
            int i = base + (((t & ~(j - 1)) << 1) | (t & (j - 1)));
            int p = i | j;
            unsigned long long a = s[i], b = s[p];
            if (a > b) { s[i] = b; s[p] = a; }
        }
        __syncthreads();
    }
    if (half == 0 && threadIdx.x == 0) *ecntE = 0;
    for (int l = threadIdx.x; l < 4096; l += 1024) {
        int gi = base + l;
        unsigned int o = (unsigned int)(s[gi] & 0xffffffffull);
        order[gi] = o;
        sb[gi] = ((const float4*)bboxes)[o];
        float c0 = conf[2 * o], c1 = conf[2 * o + 1];
        unsigned long long vb = __ballot((c0 > THR_C) || (c1 > THR_C));
        if ((gi & 63) == 0) validw[gi >> 6] = vb;
    }
}

// ---------------------------------------------------------------------------
// Kernel 3: suppression bit-matrix (fallback only) + COMPACT EDGE LIST.
//   mask[i][w] bit b = (iou(i, 64w+b) > thr && 64w+b > i) — stored for valid
//   rows only (fallback path reads only valid rows).
//   edges[] = (src << 13) | tgt for every edge with valid src AND valid tgt
//   (invalid targets can never be kept; dropping those edges is semantics-
//   preserving and ~halves the list). Wave-aggregated append: 6-step shfl
//   prefix-sum, one atomicAdd per wave.
// ---------------------------------------------------------------------------
__global__ void mask_kernel(const float4* __restrict__ sb,
                            const unsigned long long* __restrict__ validw,
                            unsigned long long* __restrict__ mask,
                            unsigned int* __restrict__ edges,
                            int* __restrict__ ecntE,
                            int ecap) {
    __shared__ float4 cb[64];
    __shared__ float carea[64];
    int w = blockIdx.y;
    if (threadIdx.x < 64) {
        float4 c = sb[(w << 6) + threadIdx.x];
        cb[threadIdx.x] = c;
        carea[threadIdx.x] = (c.z - c.x) * (c.w - c.y);
    }
    __syncthreads();
    int i = blockIdx.x * 256 + threadIdx.x;
    bool iv = (validw[i >> 6] >> (i & 63)) & 1ull;
    int jbase = w << 6;
    unsigned long long bits = 0ull;
    if (iv && (jbase + 63 > i)) {
        float4 r = sb[i];
        float ra = (r.z - r.x) * (r.w - r.y);
#pragma unroll 8
        for (int b = 0; b < 64; ++b) {
            float4 c = cb[b];
            float iw = fminf(r.z, c.z) - fmaxf(r.x, c.x);
            float ih = fminf(r.w, c.w) - fmaxf(r.y, c.y);
            iw = fmaxf(iw, 0.0f);
            ih = fmaxf(ih, 0.0f);
            float inter = iw * ih;
            float iou = inter / (ra + carea[b] - inter + EPS_C);
            if ((iou > IOU_THR_C) && ((jbase + b) > i)) bits |= (1ull << b);
        }
    }
    if (iv) mask[(size_t)i * NW + w] = bits;
    // edge append (valid targets only)
    unsigned long long ebits = bits & validw[w];
    int lane = threadIdx.x & 63;
    int ec = __popcll(ebits);
    int pre = ec;
#pragma unroll
    for (int d = 1; d < 64; d <<= 1) {
        int vv = __shfl_up(pre, d, 64);
        if (lane >= d) pre += vv;
    }
    int tot = __shfl(pre, 63, 64);
    if (tot > 0) {
        int base = 0;
        if (lane == 63) base = atomicAdd(ecntE, tot);
        base = __shfl(base, 63, 64);
        int idx = base + pre - ec;
        unsigned long long tb = ebits;
        while (tb) {
            int b = __builtin_ctzll(tb); tb &= tb - 1;
            if (idx < ecap) edges[idx] = ((unsigned int)i << 13) | (unsigned int)(jbase + b);
            ++idx;
        }
    }
}

// ---------------------------------------------------------------------------
// Kernel 4: Jacobi-iterated greedy NMS over the edge list + fused output.
// Greedy NMS is the unique fixpoint of k[i] = v[i] & ~OR_{j<i,e(j,i)} k[j].
// Jacobi sweeps (k^{t+1}[i] = v[i] & ~OR k^t[j]) are exact for every node of
// dependency depth <= t-1, so the loop converges to the greedy solution and
// k_new == k_old certifies it (unique fixpoint). Each sweep is parallel over
// edges (1024 threads); ~3 barriers/sweep. Overflow (cnt > ecap) falls back
// to the serial mask-matrix scan (correctness insurance, never expected).
// ---------------------------------------------------------------------------
__global__ __launch_bounds__(1024) void scan_kernel(const unsigned int* __restrict__ edges,
                                                    const int* __restrict__ ecntE,
                                                    const unsigned long long* __restrict__ validw,
                                                    const unsigned long long* __restrict__ mask,
                                                    const float4* __restrict__ sb,
                                                    const unsigned int* __restrict__ order,
                                                    const float* __restrict__ conf,
                                                    float* __restrict__ out,
                                                    int ecap) {
    __shared__ unsigned int eL[LCAP];             // 96 KiB
    __shared__ unsigned long long kL[NW], tL[NW], vL[NW];
    __shared__ int chg[3];
    int t = threadIdx.x;
    int cnt = *ecntE;
    if (t < NW) { unsigned long long v = validw[t]; vL[t] = v; kL[t] = v; }
    if (t == 0) { chg[0] = 0; chg[1] = 0; chg[2] = 0; }
    if (cnt <= ecap) {
        int lim = cnt < LCAP ? cnt : LCAP;
        for (int e = t; e < lim; e += 1024) eL[e] = edges[e];
    }
    __syncthreads();
    if (cnt <= ecap) {
        for (int it = 0; it < N_BOX; ++it) {
            if (t < NW) tL[t] = 0ull;
            __syncthreads();
            for (int e = t; e < cnt; e += 1024) {
                unsigned int ed = (e < LCAP) ? eL[e] : edges[e];
                int src = (int)(ed >> 13);
                if ((kL[src >> 6] >> (src & 63)) & 1ull) {
                    int tg = (int)(ed & 8191u);
                    atomicOr(&tL[tg >> 6], 1ull << (tg & 63));
                }
            }
            __syncthreads();
            if (t < NW) {
                unsigned long long nk = vL[t] & ~tL[t];
                if (nk != kL[t]) chg[it % 3] = 1;
                kL[t] = nk;
            }
            if (t == 0) chg[(it + 2) % 3] = 0;   // reset 2 barriers before reuse
            __syncthreads();
            if (chg[it % 3] == 0) break;         // uniform: read after barrier
        }
    } else if (t < 64) {
        // fallback: serial greedy over the mask matrix (one wave)
        int lane = t;
        unsigned long long r0 = ~vL[lane], r1 = ~vL[lane + 64];
        for (int w = 0; w < NW; ++w) {
            unsigned long long cur = bcast64(w < 64 ? r0 : r1, w & 63);
            for (int b = 0; b < 64; ++b) {
                if (!((cur >> b) & 1ull)) {
                    const unsigned long long* rowp = mask + (size_t)((w << 6) + b) * NW;
                    unsigned long long dw = rowp[w];
                    r0 |= rowp[lane];
                    r1 |= rowp[lane + 64];
                    cur |= dw;
                }
            }
        }
        kL[lane] = ~r0;
        kL[lane + 64] = ~r1;
    }
    __syncthreads();
    // fused output: [boxes*SCALER*kf, conf*kf]  (kL bit = KEEP)
    for (int i = t; i < N_BOX; i += 1024) {
        float kf = ((kL[i >> 6] >> (i & 63)) & 1ull) ? 1.0f : 0.0f;
        float4 b = sb[i];
        unsigned int o = order[i];
        float s = kScaler * kf;
        out[i * 6 + 0] = b.x * s;
        out[i * 6 + 1] = b.y * s;
        out[i * 6 + 2] = b.z * s;
        out[i * 6 + 3] = b.w * s;
        out[i * 6 + 4] = conf[2 * o] * kf;
        out[i * 6 + 5] = conf[2 * o + 1] * kf;
    }
}

extern "C" void kernel_launch(void* const* d_in, const int* in_sizes, int n_in,
                              void* d_out, int out_size, void* d_ws, size_t ws_size,
                              hipStream_t stream) {
    const float* cls_conf = (const float*)d_in[0];   // (8192, 2)
    const float* bboxes   = (const float*)d_in[1];   // (8192, 4)
    float* out = (float*)d_out;                      // (8192, 6)

    char* ws = (char*)d_ws;
    unsigned long long* keys   = (unsigned long long*)(ws + 0);        //  64 KiB
    float4*             sb     = (float4*)(ws + 65536);                // 128 KiB
    unsigned int*       order  = (unsigned int*)(ws + 196608);         //  32 KiB
    unsigned long long* validw = (unsigned long long*)(ws + 229376);   //   1 KiB
    int*                ecntE  = (int*)(ws + 230400);                  //   4 B
    unsigned long long* mask   = (unsigned long long*)(ws + 237568);   //   8 MiB
    const size_t EDGE_OFF = 8626176;                                   // after mask
    unsigned int*       edges  = (unsigned int*)(ws + EDGE_OFF);
    size_t avail = (ws_size > EDGE_OFF + 16) ? (ws_size - EDGE_OFF) / 4 : 0;
    int ecap = (int)(avail > (size_t)ECAP_MAX ? (size_t)ECAP_MAX : avail);

    sort_local1<<<4, 1024, 0, stream>>>(cls_conf, keys);
    sort_mid<<<2, 1024, 0, stream>>>(keys);
    sort_final<<<2, 1024, 0, stream>>>(keys, bboxes, cls_conf, sb, order, validw, ecntE);
    mask_kernel<<<dim3(32, 128), 256, 0, stream>>>(sb, validw, mask, edges, ecntE, ecap);
    scan_kernel<<<1, 1024, 0, stream>>>(edges, ecntE, validw, mask, sb, order,
                                        cls_conf, out, ecap);
}

// Round 9
// 133.677 us; speedup vs baseline: 2.8579x; 1.1631x over previous
//
#include <hip/hip_runtime.h>
#include <math.h>

#define N_BOX 8192
#define NW 128              // 8192 / 64 words per row
#define LCAP 24576          // edges staged in LDS (96 KiB)
#define ECAP_MAX (1 << 21)  // max edges in global buffer (8 MiB)
#define THR_C 0.7f
#define IOU_THR_C 0.5f
#define EPS_C 1e-9f

// SCALER = max(3508/1280, 2480/1280) computed in double then rounded to f32,
// matching numpy/jax float32 weak-typed scalar promotion.
__device__ __constant__ float kScaler = (float)(3508.0 / 1280.0);

static __device__ __forceinline__ unsigned long long make_key(const float* conf, int i) {
    float c0 = conf[2 * i], c1 = conf[2 * i + 1];
    bool valid = (c0 > THR_C) || (c1 > THR_C);
    float ms = valid ? fmaxf(c0, c1) : -INFINITY;
    unsigned int u = __float_as_uint(ms);
    unsigned int m = (u & 0x80000000u) ? ~u : (u | 0x80000000u); // ascending map
    unsigned int d = ~m;                                          // descending key
    return ((unsigned long long)d << 32) | (unsigned int)i;
}

// ---------------------------------------------------------------------------
// Sort stage 1: 4 blocks x 2048 elements, all k<=2048 passes LDS-local.
// Directions use GLOBAL indices -> network identical to the verified
// single-block bitonic sort. Block 0 also zero-inits the global counters.
// ---------------------------------------------------------------------------
__global__ __launch_bounds__(1024) void sort_local1(const float* __restrict__ conf,
                                                    unsigned long long* __restrict__ keys,
                                                    int* __restrict__ ecntE,
                                                    int* __restrict__ nvD) {
    __shared__ unsigned long long s[2048];
    int base = blockIdx.x * 2048;
    if (blockIdx.x == 0 && threadIdx.x == 0) { *ecntE = 0; *nvD = 0; }
    for (int l = threadIdx.x; l < 2048; l += 1024) s[l] = make_key(conf, base + l);
    __syncthreads();
    for (int k = 2; k <= 2048; k <<= 1) {
        for (int j = k >> 1; j > 0; j >>= 1) {
            int t = threadIdx.x;
            int i = ((t & ~(j - 1)) << 1) | (t & (j - 1));
            int p = i | j;
            bool up = (((base + i) & k) == 0);
            unsigned long long a = s[i], b = s[p];
            bool sw = up ? (a > b) : (a < b);
            if (sw) { s[i] = b; s[p] = a; }
            __syncthreads();
        }
    }
    for (int l = threadIdx.x; l < 2048; l += 1024) keys[base + l] = s[l];
}

// ---------------------------------------------------------------------------
// Sort stage 2 (fused k=4096 + k=8192) + gather. Each of 2 blocks loads ALL
// 8192 keys, runs the k=4096 merge phases on the full array in LDS (identical
// indices/directions to the old sort_mid), then the k=8192 j=4096 cross
// exchange for its own half, then j=2048..1 locally (all ascending), then
// consumes the sorted half directly from LDS: writes sb/order/validw and
// accumulates nv (valid count) — valid boxes occupy ranks [0, nv).
// ---------------------------------------------------------------------------
__global__ __launch_bounds__(1024) void sort_final2(const unsigned long long* __restrict__ keys,
                                                    const float* __restrict__ bboxes,
                                                    const float* __restrict__ conf,
                                                    float4* __restrict__ sb,
                                                    unsigned int* __restrict__ order,
                                                    unsigned long long* __restrict__ validw,
                                                    int* __restrict__ nvD) {
    __shared__ unsigned long long s[8192];   // 64 KiB
    int half = blockIdx.x;                   // 0 or 1
    int base = half << 12;
    int t = threadIdx.x;
    for (int l = t; l < 8192; l += 1024) s[l] = keys[l];
    __syncthreads();
    // k=4096 merge on the full array (replaces sort_mid)
    for (int j = 2048; j > 0; j >>= 1) {
        for (int t2 = t; t2 < 4096; t2 += 1024) {
            int i = ((t2 & ~(j - 1)) << 1) | (t2 & (j - 1));
            int p = i | j;
            bool up = ((i & 4096) == 0);
            unsigned long long a = s[i], b = s[p];
            bool sw = up ? (a > b) : (a < b);
            if (sw) { s[i] = b; s[p] = a; }
        }
        __syncthreads();
    }
    // k=8192, j=4096: min -> low half, max -> high half (all ascending)
    unsigned long long v[4];
#pragma unroll
    for (int q = 0; q < 4; ++q) {
        int l = t + (q << 10);               // 0..4095
        unsigned long long a = s[l], b = s[l + 4096];
        v[q] = half ? (a > b ? a : b) : (a > b ? b : a);
    }
    __syncthreads();
#pragma unroll
    for (int q = 0; q < 4; ++q) s[base + t + (q << 10)] = v[q];
    __syncthreads();
    // j=2048..1, own half, all ascending (k=8192)
    for (int j = 2048; j > 0; j >>= 1) {
        for (int t2 = t; t2 < 2048; t2 += 1024) {
            int i = base + (((t2 & ~(j - 1)) << 1) | (t2 & (j - 1)));
            int p = i | j;
            unsigned long long a = s[i], b = s[p];
            if (a > b) { s[i] = b; s[p] = a; }
        }
        __syncthreads();
    }
    for (int l = t; l < 4096; l += 1024) {
        int gi = base + l;
        unsigned int o = (unsigned int)(s[gi] & 0xffffffffull);
        order[gi] = o;
        sb[gi] = ((const float4*)bboxes)[o];
        float c0 = conf[2 * o], c1 = conf[2 * o + 1];
        unsigned long long vb = __ballot((c0 > THR_C) || (c1 > THR_C));
        if ((gi & 63) == 0) {
            validw[gi >> 6] = vb;
            atomicAdd(nvD, __popcll(vb));
        }
    }
}

// ---------------------------------------------------------------------------
// Kernel 3: pair kernel — COMPACT EDGE LIST only (no mask matrix).
// Valid boxes are exactly ranks [0,nv) (invalid sort last with -inf keys), so
// the IoU domain is the nv x nv upper triangle. Whole blocks outside it exit
// immediately. Edge = (src<<13)|tgt, both valid, iou > thr, tgt > src; exact
// IEEE fp32 arithmetic identical to the reference. Wave-aggregated append.
// ---------------------------------------------------------------------------
__global__ void pair_kernel(const float4* __restrict__ sb,
                            const int* __restrict__ nvD,
                            unsigned int* __restrict__ edges,
                            int* __restrict__ ecntE,
                            int ecap) {
    int w = blockIdx.y;
    int jbase = w << 6;
    int ibase = blockIdx.x * 256;
    int nv = *nvD;
    if (ibase >= nv || jbase >= nv || jbase + 63 <= ibase) return;  // uniform
    __shared__ float4 cb[64];
    __shared__ float carea[64];
    if (threadIdx.x < 64) {
        float4 c = sb[jbase + threadIdx.x];
        cb[threadIdx.x] = c;
        carea[threadIdx.x] = (c.z - c.x) * (c.w - c.y);
    }
    __syncthreads();
    int i = ibase + threadIdx.x;
    unsigned long long bits = 0ull;
    if (i < nv && jbase + 63 > i) {
        float4 r = sb[i];
        float ra = (r.z - r.x) * (r.w - r.y);
#pragma unroll 8
        for (int b = 0; b < 64; ++b) {
            float4 c = cb[b];
            float iw = fminf(r.z, c.z) - fmaxf(r.x, c.x);
            float ih = fminf(r.w, c.w) - fmaxf(r.y, c.y);
            iw = fmaxf(iw, 0.0f);
            ih = fmaxf(ih, 0.0f);
            float inter = iw * ih;
            float iou = inter / (ra + carea[b] - inter + EPS_C);
            if ((iou > IOU_THR_C) && ((jbase + b) > i)) bits |= (1ull << b);
        }
    }
    // drop targets >= nv (invalid: can never be kept)
    unsigned long long tmask = (jbase + 64 <= nv) ? ~0ull
                               : ((1ull << (nv - jbase)) - 1ull);
    unsigned long long ebits = bits & tmask;
    int lane = threadIdx.x & 63;
    int ec = __popcll(ebits);
    int pre = ec;
#pragma unroll
    for (int d = 1; d < 64; d <<= 1) {
        int vv = __shfl_up(pre, d, 64);
        if (lane >= d) pre += vv;
    }
    int tot = __shfl(pre, 63, 64);
    if (tot > 0) {
        int base = 0;
        if (lane == 63) base = atomicAdd(ecntE, tot);
        base = __shfl(base, 63, 64);
        int idx = base + pre - ec;
        unsigned long long tb = ebits;
        while (tb) {
            int b = __builtin_ctzll(tb); tb &= tb - 1;
            if (idx < ecap) edges[idx] = ((unsigned int)i << 13) | (unsigned int)(jbase + b);
            ++idx;
        }
    }
}

// ---------------------------------------------------------------------------
// Kernel 4: Jacobi-iterated greedy NMS over the edge list (256 threads).
// Greedy NMS is the unique fixpoint of k[i] = v[i] & ~OR_{j<i,e(j,i)} k[j];
// Jacobi sweeps are exact for nodes of dependency depth <= t-1, so k_new ==
// k_old certifies convergence to the greedy solution. 4-wave barriers keep
// per-sweep cost low. Overflow (cnt > ecap, never expected) falls back to an
// on-the-fly serial greedy recomputing IoU from sb — slow but correct.
// ---------------------------------------------------------------------------
__global__ __launch_bounds__(256) void scan_kernel(const unsigned int* __restrict__ edges,
                                                   const int* __restrict__ ecntE,
                                                   const unsigned long long* __restrict__ validw,
                                                   const float4* __restrict__ sb,
                                                   unsigned long long* __restrict__ keepK,
                                                   int ecap) {
    __shared__ unsigned int eL[LCAP];             // 96 KiB
    __shared__ unsigned long long kL[NW], tL[NW], vL[NW];
    __shared__ int chg[3];
    int t = threadIdx.x;
    int cnt = *ecntE;
    if (t < NW) { unsigned long long v = validw[t]; vL[t] = v; kL[t] = v; }
    if (t == 0) { chg[0] = 0; chg[1] = 0; chg[2] = 0; }
    if (cnt <= ecap) {
        int lim = cnt < LCAP ? cnt : LCAP;
        for (int e = t; e < lim; e += 256) eL[e] = edges[e];
    }
    __syncthreads();
    if (cnt <= ecap) {
        for (int it = 0; it < N_BOX; ++it) {
            if (t < NW) tL[t] = 0ull;
            __syncthreads();
            for (int e = t; e < cnt; e += 256) {
                unsigned int ed = (e < LCAP) ? eL[e] : edges[e];
                int src = (int)(ed >> 13);
                if ((kL[src >> 6] >> (src & 63)) & 1ull) {
                    int tg = (int)(ed & 8191u);
                    atomicOr(&tL[tg >> 6], 1ull << (tg & 63));
                }
            }
            __syncthreads();
            if (t < NW) {
                unsigned long long nk = vL[t] & ~tL[t];
                if (nk != kL[t]) chg[it % 3] = 1;
                kL[t] = nk;
            }
            if (t == 0) chg[(it + 2) % 3] = 0;   // reset 2 barriers before reuse
            __syncthreads();
            if (chg[it % 3] == 0) break;         // uniform: read after barrier
        }
    } else {
        // fallback: serial greedy, IoU recomputed on the fly (one wave)
        if (t < NW) tL[t] = ~vL[t];              // removed = !valid
        __syncthreads();
        if (t < 64) {
            int lane = t;
            for (int i = 0; i < N_BOX - 1; ++i) {
                bool kept = !((tL[i >> 6] >> (i & 63)) & 1ull);
                if (kept) {
                    float4 r = sb[i];
                    float ra = (r.z - r.x) * (r.w - r.y);
                    for (int j = i + 1 + lane; j < N_BOX; j += 64) {
                        float4 c = sb[j];
                        float ca = (c.z - c.x) * (c.w - c.y);
                        float iw = fminf(r.z, c.z) - fmaxf(r.x, c.x);
                        float ih = fminf(r.w, c.w) - fmaxf(r.y, c.y);
                        iw = fmaxf(iw, 0.0f);
                        ih = fmaxf(ih, 0.0f);
                        float inter = iw * ih;
                        float iou = inter / (ra + ca - inter + EPS_C);
                        if (iou > IOU_THR_C) atomicOr(&tL[j >> 6], 1ull << (j & 63));
                    }
                }
            }
        }
        __syncthreads();
        if (t < NW) kL[t] = vL[t] & ~tL[t];
    }
    __syncthreads();
    if (t < NW) keepK[t] = kL[t];
}

// ---------------------------------------------------------------------------
// Kernel 5: write (N,6) output: [boxes*SCALER*kf, conf*kf]  (keep bit = 1)
// ---------------------------------------------------------------------------
__global__ void out_kernel(const float4* __restrict__ sb,
                           const unsigned long long* __restrict__ keepK,
                           const unsigned int* __restrict__ order,
                           const float* __restrict__ conf,
                           float* __restrict__ out) {
    int i = blockIdx.x * 256 + threadIdx.x;
    float kf = ((keepK[i >> 6] >> (i & 63)) & 1ull) ? 1.0f : 0.0f;
    float4 b = sb[i];
    unsigned int o = order[i];
    float s = kScaler * kf;
    out[i * 6 + 0] = b.x * s;
    out[i * 6 + 1] = b.y * s;
    out[i * 6 + 2] = b.z * s;
    out[i * 6 + 3] = b.w * s;
    out[i * 6 + 4] = conf[2 * o] * kf;
    out[i * 6 + 5] = conf[2 * o + 1] * kf;
}

extern "C" void kernel_launch(void* const* d_in, const int* in_sizes, int n_in,
                              void* d_out, int out_size, void* d_ws, size_t ws_size,
                              hipStream_t stream) {
    const float* cls_conf = (const float*)d_in[0];   // (8192, 2)
    const float* bboxes   = (const float*)d_in[1];   // (8192, 4)
    float* out = (float*)d_out;                      // (8192, 6)

    char* ws = (char*)d_ws;
    unsigned long long* keys   = (unsigned long long*)(ws + 0);        //  64 KiB
    float4*             sb     = (float4*)(ws + 65536);                // 128 KiB
    unsigned int*       order  = (unsigned int*)(ws + 196608);         //  32 KiB
    unsigned long long* validw = (unsigned long long*)(ws + 229376);   //   1 KiB
    int*                ecntE  = (int*)(ws + 230400);                  //   4 B
    int*                nvD    = (int*)(ws + 230408);                  //   4 B
    unsigned long long* keepK  = (unsigned long long*)(ws + 230912);   //   1 KiB
    const size_t EDGE_OFF = 237568;
    unsigned int*       edges  = (unsigned int*)(ws + EDGE_OFF);
    size_t avail = (ws_size > EDGE_OFF + 16) ? (ws_size - EDGE_OFF) / 4 : 0;
    int ecap = (int)(avail > (size_t)ECAP_MAX ? (size_t)ECAP_MAX : avail);

    sort_local1<<<4, 1024, 0, stream>>>(cls_conf, keys, ecntE, nvD);
    sort_final2<<<2, 1024, 0, stream>>>(keys, bboxes, cls_conf, sb, order, validw, nvD);
    pair_kernel<<<dim3(32, 128), 256, 0, stream>>>(sb, nvD, edges, ecntE, ecap);
    scan_kernel<<<1, 256, 0, stream>>>(edges, ecntE, validw, sb, keepK, ecap);
    out_kernel<<<N_BOX / 256, 256, 0, stream>>>(sb, keepK, order, cls_conf, out);
}